// Round 10
// baseline (139.838 us; speedup 1.0000x reference)
//
#include <hip/hip_runtime.h>
#include <cstdint>
#include <cstddef>

using f16   = _Float16;
using half8 = __attribute__((ext_vector_type(8))) _Float16;
using f32x4 = __attribute__((ext_vector_type(4))) float;
using ull   = unsigned long long;

#define DINL __device__ __forceinline__

// global -> LDS async, 16B per lane. LDS dest wave-uniform base + lane*16.
DINL void gload_lds16(const void* gptr, void* lptr) {
  __builtin_amdgcn_global_load_lds(
      reinterpret_cast<const __attribute__((address_space(1))) uint32_t*>(
          reinterpret_cast<uintptr_t>(gptr)),
      reinterpret_cast<__attribute__((address_space(3))) uint32_t*>(
          reinterpret_cast<uintptr_t>(lptr)),
      16, 0, 0);
}

DINL unsigned pkh(float a, float b) {
  unsigned short ha = __builtin_bit_cast(unsigned short, (f16)a);
  unsigned short hb = __builtin_bit_cast(unsigned short, (f16)b);
  return (unsigned)ha | ((unsigned)hb << 16);
}

struct U4 { unsigned x, y, z, w; };

// x -> 16B A-fragment: [B0..B5 uniform cubic B-spline, silu(x), 0] as 8 f16.
// EXACTLY the numerics of rounds 5-9 (absmax 0.03125) — untouched.
DINL U4 expand_pack(float x) {
  float xs = (x + 3.0f) * 1.5f;
  float mf = floorf(xs);
  int   m  = (int)mf;
  float u = xs - mf, u2 = u * u, u3 = u2 * u, um = 1.0f - u;
  float p3 = u3 * (1.0f / 6.0f);
  float p2 = (1.0f + 3.0f * (u + u2 - u3)) * (1.0f / 6.0f);
  float p1 = (4.0f - 6.0f * u2 + 3.0f * u3) * (1.0f / 6.0f);
  float p0 = um * um * um * (1.0f / 6.0f);
  ull P = (ull)pkh(p0, p1) | ((ull)pkh(p2, p3) << 32);
  if ((unsigned)m > 8u) P = 0;
  int s    = m * 16 - 48;
  int sneg = min(63, max(0, -s));
  int spos = min(63, max(0, s));
  int shi2 = min(63, max(0, s - 64));
  ull rlo = (s < 0) ? (P >> sneg) : ((s < 64) ? (P << spos) : 0ull);
  ull rhi = (s < 0) ? 0ull
                    : ((s < 64) ? ((P >> (63 - spos)) >> 1) : (P << shi2));
  float sil = x / (1.0f + __expf(-x));
  U4 r;
  r.x = (unsigned)rlo;
  r.y = (unsigned)(rlo >> 32);
  r.z = (unsigned)rhi;
  r.w = pkh(sil, 0.0f);
  return r;
}

// Weight prep, PRE-SWIZZLED (rule 21): dim slot stored at (d&7)^(n&7) so a
// linear global_load_lds yields the swizzled LDS tile. Validated rounds 2-9.
__global__ __launch_bounds__(256)
void prep_w_kernel(const float* __restrict__ coef, const float* __restrict__ ssp,
                   const float* __restrict__ sb, f16* __restrict__ Wt,
                   int Din, int Dout) {
  int idx = blockIdx.x * 256 + threadIdx.x;
  if (idx >= Din * Dout) return;
  int n = idx / Din;
  int d = idx - n * Din;
  float s = ssp[(size_t)d * Dout + n];
  const float* c = coef + ((size_t)d * Dout + n) * 6;
  half8 wv;
#pragma unroll
  for (int b = 0; b < 6; ++b) wv[b] = (f16)(c[b] * s);
  wv[6] = (f16)sb[(size_t)d * Dout + n];
  wv[7] = (f16)0.0f;
  int dp = (d & ~7) | ((d & 7) ^ (n & 7));
  *reinterpret_cast<half8*>(Wt + ((size_t)n * Din + dp) * 8) = wv;
}

// ---------------------------------------------------------------------------
// Fused KAN GEMM v10 — A-fragment-in-register design.
// Each wave owns 16 m-rows x 128 n. expand_pack(x) IS the MFMA A-operand
// fragment (lane(l15,hi) = A[row=l15][k=hi*8..+7] = 8 channels of one dim):
// no A-LDS, no A ds_write/read, no A swizzle, no A barrier dependency.
// W: pre-swizzled LDS tile (proven); x: raw floats via 4KB LDS bounce
// (coalesced gload_lds in, 2-way-free ds_read out).
// BM=128 (8 waves x 16), BN=128, BK=64 (8 dims/step), dbuf, 40KB LDS,
// grid 512 blocks -> 2 blocks/CU, 4 waves/SIMD. Split-K via blockIdx.z.
// ---------------------------------------------------------------------------
template <bool BIAS, int NS>
__global__ __launch_bounds__(512, 4)
void kan_gemm(const float* __restrict__ X, int ldx,
              const f16* __restrict__ Wt, int ldw,
              const float* __restrict__ nscale, const float* __restrict__ nbias,
              int N, float* __restrict__ Out) {
  __shared__ alignas(16) f16   WB0[128 * 64];   // 16 KB
  __shared__ alignas(16) f16   WB1[128 * 64];   // 16 KB
  __shared__ alignas(16) float XB0[128 * 8];    //  4 KB
  __shared__ alignas(16) float XB1[128 * 8];    //  4 KB

  const int tid  = threadIdx.x;
  const int w    = tid >> 6;
  const int lane = tid & 63;
  const int l15  = lane & 15, l7 = lane & 7, hi = lane >> 4;
  const int m0   = blockIdx.y * 128;
  const int n0   = blockIdx.x * 128;
  const int dim0 = blockIdx.z * (NS * 8);
  float* outz = Out + (size_t)blockIdx.z * ((size_t)gridDim.y * 128) * N;

  // W staging: 2 x 16B chunks/thread (128 rows x 8 slots = 1024 chunks)
  const f16* wsrc0 = Wt + (size_t)(n0 + (tid >> 3)) * ldw + (size_t)dim0 * 8 + (tid & 7) * 8;
  const f16* wsrc1 = Wt + (size_t)(n0 + ((tid + 512) >> 3)) * ldw + (size_t)dim0 * 8 + (tid & 7) * 8;
  const int  wdst0 = tid * 8;            // f16 elems
  const int  wdst1 = (tid + 512) * 8;

  // X staging: threads 0-255 stage 16B each (128 rows x 32B per step)
  const bool  xstager = (tid < 256);
  const float* xsrc = X + (size_t)(m0 + (tid >> 1)) * ldx + dim0 + (tid & 1) * 4;
  const int   xdst  = tid * 4;           // float elems

  // my x read slot: row = w*16 + l15, dim = hi (kk=0) / hi+4 (kk=1)
  const int xro = (w * 16 + l15) * 8 + hi;

  f32x4 acc[8] = {};

  auto stageW = [&](f16* buf, int ke) {
    gload_lds16(wsrc0 + ke, buf + wdst0);
    gload_lds16(wsrc1 + ke, buf + wdst1);
  };
  auto stageX = [&](float* buf, int s) {
    if (xstager) gload_lds16(xsrc + s * 8, buf + xdst);
  };

  auto step = [&](const float* xb, const f16* wb) {
    float x0 = xb[xro];
    float x1 = xb[xro + 4];
    U4 e0 = expand_pack(x0);
    U4 e1 = expand_pack(x1);
    half8 a0 = __builtin_bit_cast(half8, e0);
    half8 a1 = __builtin_bit_cast(half8, e1);
#pragma unroll
    for (int j = 0; j < 8; ++j) {
      half8 bv = *reinterpret_cast<const half8*>(
          wb + (j * 16 + l15) * 64 + 8 * (hi ^ l7));
      acc[j] = __builtin_amdgcn_mfma_f32_16x16x32_f16(a0, bv, acc[j], 0, 0, 0);
    }
#pragma unroll
    for (int j = 0; j < 8; ++j) {
      half8 bv = *reinterpret_cast<const half8*>(
          wb + (j * 16 + l15) * 64 + 8 * ((4 + hi) ^ l7));
      acc[j] = __builtin_amdgcn_mfma_f32_16x16x32_f16(a1, bv, acc[j], 0, 0, 0);
    }
  };

  // ---- prologue: tile 0 staged ----
  stageW(WB0, 0);
  stageX(XB0, 0);
  __syncthreads();

  // ---- steady state: 2 steps per iteration, static buffer names ----
  int ke = 64;   // W k-elem offset of step 2p+1
  int sx = 1;
  for (int p = 0; p < NS / 2 - 1; ++p) {
    stageW(WB1, ke);       stageX(XB1, sx);
    step(XB0, WB0);
    __syncthreads();
    stageW(WB0, ke + 64);  stageX(XB0, sx + 1);
    step(XB1, WB1);
    __syncthreads();
    ke += 128; sx += 2;
  }

  // ---- tail: steps NS-2 and NS-1 ----
  stageW(WB1, (NS - 1) * 64);
  stageX(XB1, NS - 1);
  step(XB0, WB0);
  __syncthreads();
  step(XB1, WB1);

  // ---- epilogue: Out = ns*acc (+ nb) ----
#pragma unroll
  for (int j = 0; j < 8; ++j) {
    int col   = n0 + j * 16 + l15;
    float nsv = nscale[col];
    float nbv = BIAS ? nbias[col] : 0.0f;
    int rowb  = m0 + w * 16 + hi * 4;
#pragma unroll
    for (int r = 0; r < 4; ++r)
      outz[(size_t)(rowb + r) * N + col] = nsv * acc[j][r] + nbv;
  }
}

// ---------------------------------------------------------------------------
// partial0 + partial1 + node_bias2 + residual -> LayerNorm(256) -> exact GELU
// ---------------------------------------------------------------------------
__global__ __launch_bounds__(256)
void ln_gelu_kernel(const float* __restrict__ P0, const float* __restrict__ P1,
                    const float* __restrict__ X,  const float* __restrict__ nb2,
                    const float* __restrict__ gamma, const float* __restrict__ beta,
                    float* __restrict__ out, int rows) {
  int row  = blockIdx.x * 4 + (threadIdx.x >> 6);
  int lane = threadIdx.x & 63;
  if (row >= rows) return;
  const float4 a  = *reinterpret_cast<const float4*>(P0 + (size_t)row * 256 + lane * 4);
  const float4 b  = *reinterpret_cast<const float4*>(P1 + (size_t)row * 256 + lane * 4);
  const float4 xr = *reinterpret_cast<const float4*>(X  + (size_t)row * 256 + lane * 4);
  const float4 nb = *reinterpret_cast<const float4*>(nb2 + lane * 4);
  const float4 g  = *reinterpret_cast<const float4*>(gamma + lane * 4);
  const float4 be = *reinterpret_cast<const float4*>(beta + lane * 4);
  float h[4] = { a.x + b.x + nb.x + xr.x, a.y + b.y + nb.y + xr.y,
                 a.z + b.z + nb.z + xr.z, a.w + b.w + nb.w + xr.w };
  float s = h[0] + h[1] + h[2] + h[3];
#pragma unroll
  for (int o = 32; o >= 1; o >>= 1) s += __shfl_xor(s, o);
  float mu = s * (1.0f / 256.0f);
  float vs = 0.f;
#pragma unroll
  for (int j = 0; j < 4; ++j) { float d = h[j] - mu; vs += d * d; }
#pragma unroll
  for (int o = 32; o >= 1; o >>= 1) vs += __shfl_xor(vs, o);
  float inv = rsqrtf(vs * (1.0f / 256.0f) + 1e-5f);
  float o4[4];
#pragma unroll
  for (int j = 0; j < 4; ++j) {
    float gj = (&g.x)[j], bj = (&be.x)[j];
    float v = (h[j] - mu) * inv * gj + bj;
    o4[j] = 0.5f * v * (1.0f + erff(v * 0.70710678118654752f));
  }
  *reinterpret_cast<float4*>(out + (size_t)row * 256 + lane * 4) =
      make_float4(o4[0], o4[1], o4[2], o4[3]);
}

// ---------------------------------------------------------------------------
extern "C" void kernel_launch(void* const* d_in, const int* in_sizes, int n_in,
                              void* d_out, int out_size, void* d_ws, size_t ws_size,
                              hipStream_t stream) {
  (void)in_sizes; (void)n_in; (void)out_size; (void)ws_size;
  const float* x     = (const float*)d_in[0];
  const float* coef1 = (const float*)d_in[2];
  const float* sb1   = (const float*)d_in[3];
  const float* ssp1  = (const float*)d_in[4];
  const float* ns1   = (const float*)d_in[5];
  const float* nb1   = (const float*)d_in[6];
  const float* coef2 = (const float*)d_in[8];
  const float* sb2   = (const float*)d_in[9];
  const float* ssp2  = (const float*)d_in[10];
  const float* ns2   = (const float*)d_in[11];
  const float* nb2   = (const float*)d_in[12];
  const float* lgam  = (const float*)d_in[13];
  const float* lbet  = (const float*)d_in[14];
  float* out = (float*)d_out;

  const int Ntok = 16 * 1024;
  const int D0 = 256, D1 = 512, D2 = 256;

  // ws: h1 [Ntok,512] f32 | part [2][Ntok,256] f32 | Wt1 2MB | Wt2 2MB
  char*  ws   = (char*)d_ws;
  float* h1   = (float*)ws;
  size_t off  = (size_t)Ntok * D1 * sizeof(float);
  float* part = (float*)(ws + off);
  off += (size_t)2 * Ntok * D2 * sizeof(float);
  f16* Wt1 = (f16*)(ws + off);
  off += (size_t)D1 * D0 * 8 * sizeof(f16);
  f16* Wt2 = (f16*)(ws + off);

  prep_w_kernel<<<(D0 * D1 + 255) / 256, 256, 0, stream>>>(coef1, ssp1, sb1, Wt1, D0, D1);
  prep_w_kernel<<<(D1 * D2 + 255) / 256, 256, 0, stream>>>(coef2, ssp2, sb2, Wt2, D1, D2);

  // layer 1: [16384 x 2048] x [512 x 2048]^T -> h1.
  // 4 n-panels x 128 m-blocks = 512 blocks (2/CU).
  kan_gemm<true, 32><<<dim3(D1 / 128, Ntok / 128, 1), 512, 0, stream>>>(
      x, D0, Wt1, D0 * 8, ns1, nb1, D1, h1);

  // layer 2: 2 n-panels x 128 m-blocks x split-K 2 = 512 blocks; partials.
  kan_gemm<false, 32><<<dim3(D2 / 128, Ntok / 128, 2), 512, 0, stream>>>(
      h1, D1, Wt2, D1 * 8, ns2, nullptr, D2, part);

  // reduce partials + bias + residual + LN + GELU
  ln_gelu_kernel<<<Ntok / 4, 256, 0, stream>>>(
      part, part + (size_t)Ntok * D2, x, nb2, lgam, lbet, out, Ntok);
}

// Round 11
// 118.574 us; speedup vs baseline: 1.1793x; 1.1793x over previous
//
#include <hip/hip_runtime.h>
#include <cstdint>
#include <cstddef>

using f16   = _Float16;
using half4 = __attribute__((ext_vector_type(4))) _Float16;
using half8 = __attribute__((ext_vector_type(8))) _Float16;
using f32x4 = __attribute__((ext_vector_type(4))) float;
using ull   = unsigned long long;

#define DINL __device__ __forceinline__

// global -> LDS async, 16B per lane. LDS dest wave-uniform base + lane*16.
DINL void gload_lds16(const void* gptr, void* lptr) {
  __builtin_amdgcn_global_load_lds(
      reinterpret_cast<const __attribute__((address_space(1))) uint32_t*>(
          reinterpret_cast<uintptr_t>(gptr)),
      reinterpret_cast<__attribute__((address_space(3))) uint32_t*>(
          reinterpret_cast<uintptr_t>(lptr)),
      16, 0, 0);
}

DINL unsigned pkh(float a, float b) {
  unsigned short ha = __builtin_bit_cast(unsigned short, (f16)a);
  unsigned short hb = __builtin_bit_cast(unsigned short, (f16)b);
  return (unsigned)ha | ((unsigned)hb << 16);
}

struct U4 { unsigned x, y, z, w; };

// x -> 16B A-row: [B0..B5 uniform cubic B-spline, silu(x), 0] as 8 f16.
// Funnel-shift placement; validated rounds 5-10 (absmax 0.03125).
DINL U4 expand_pack(float x) {
  float xs = (x + 3.0f) * 1.5f;
  float mf = floorf(xs);
  int   m  = (int)mf;
  float u = xs - mf, u2 = u * u, u3 = u2 * u, um = 1.0f - u;
  float p3 = u3 * (1.0f / 6.0f);
  float p2 = (1.0f + 3.0f * (u + u2 - u3)) * (1.0f / 6.0f);
  float p1 = (4.0f - 6.0f * u2 + 3.0f * u3) * (1.0f / 6.0f);
  float p0 = um * um * um * (1.0f / 6.0f);
  ull P = (ull)pkh(p0, p1) | ((ull)pkh(p2, p3) << 32);
  if ((unsigned)m > 8u) P = 0;
  int s    = m * 16 - 48;
  int sneg = min(63, max(0, -s));
  int spos = min(63, max(0, s));
  int shi2 = min(63, max(0, s - 64));
  ull rlo = (s < 0) ? (P >> sneg) : ((s < 64) ? (P << spos) : 0ull);
  ull rhi = (s < 0) ? 0ull
                    : ((s < 64) ? ((P >> (63 - spos)) >> 1) : (P << shi2));
  float sil = x / (1.0f + __expf(-x));
  U4 r;
  r.x = (unsigned)rlo;
  r.y = (unsigned)(rlo >> 32);
  r.z = (unsigned)rhi;
  r.w = pkh(sil, 0.0f);
  return r;
}

// Weight prep, PRE-SWIZZLED (rule 21): dim slot stored at (d&7)^(n&7) so a
// linear global_load_lds yields the swizzled LDS tile. Validated rounds 2-10.
__global__ __launch_bounds__(256)
void prep_w_kernel(const float* __restrict__ coef, const float* __restrict__ ssp,
                   const float* __restrict__ sb, f16* __restrict__ Wt,
                   int Din, int Dout) {
  int idx = blockIdx.x * 256 + threadIdx.x;
  if (idx >= Din * Dout) return;
  int n = idx / Din;
  int d = idx - n * Din;
  float s = ssp[(size_t)d * Dout + n];
  const float* c = coef + ((size_t)d * Dout + n) * 6;
  half8 wv;
#pragma unroll
  for (int b = 0; b < 6; ++b) wv[b] = (f16)(c[b] * s);
  wv[6] = (f16)sb[(size_t)d * Dout + n];
  wv[7] = (f16)0.0f;
  int dp = (d & ~7) | ((d & 7) ^ (n & 7));
  *reinterpret_cast<half8*>(Wt + ((size_t)n * Din + dp) * 8) = wv;
}

// ---------------------------------------------------------------------------
// Fused KAN GEMM v11 = v8 (best measured: 54.5us/GEMM, absmax 0.03125) +
//  (a) T5: s_setprio(1) around the MFMA cluster (wave role-diversity exists:
//      stage/expand waves vs MFMA waves), (b) templated input/output dtypes
//      so h1 and split-K partials live in f16 (HBM traffic cut ~40%).
// BM=64 x BN=256, 8 waves (2x4, 32x64/wave), BK=64, static 80KB LDS dbuf,
// 1 barrier/step, K-loop unrolled x2 with static buffer names + peeled tail.
// ---------------------------------------------------------------------------
template <bool BIAS, typename TIN, typename TOUT>
__global__ __launch_bounds__(512, 4)
void kan_gemm(const TIN* __restrict__ X, int ldx,
              const f16* __restrict__ Wt, int ldw,
              const float* __restrict__ nscale, const float* __restrict__ nbias,
              int N, TOUT* __restrict__ Out, int nsteps) {
  __shared__ alignas(16) f16 A0[64 * 64];      //  8 KB
  __shared__ alignas(16) f16 A1[64 * 64];      //  8 KB
  __shared__ alignas(16) f16 B0[256 * 64];     // 32 KB
  __shared__ alignas(16) f16 B1[256 * 64];     // 32 KB

  const int tid  = threadIdx.x;
  const int w    = tid >> 6;
  const int lane = tid & 63;
  const int l15  = lane & 15, l7 = lane & 7, hi = lane >> 4;
  const int wm   = w >> 2, wn = w & 3;         // wave grid 2 x 4
  const int m0   = blockIdx.y * 64;
  const int n0   = blockIdx.x * 256;
  const int dim0 = blockIdx.z * (nsteps * 8);  // split-K dim offset
  TOUT* outz = Out + (size_t)blockIdx.z * ((size_t)gridDim.y * 64) * N;

  // A: 1 element/thread/step (64 rows x 8 dims = 512)
  const int ar = tid >> 3, ad = tid & 7;
  const TIN* asrc = X + (size_t)(m0 + ar) * ldx + dim0 + ad;
  const int aoff = ar * 64 + 8 * (ad ^ (ar & 7));

  // B: 4 x 16B chunks/thread (256 rows x 8 slots = 2048 chunks)
  const f16* wb[4];
  int ldsb[4];
#pragma unroll
  for (int q = 0; q < 4; ++q) {
    int c   = tid + q * 512;
    wb[q]   = Wt + (size_t)(n0 + (c >> 3)) * ldw + (size_t)dim0 * 8 + (c & 7) * 8;
    ldsb[q] = c * 8;
  }

  f32x4 acc[2][4] = {};

  auto stageB = [&](f16* buf, int k0) {
#pragma unroll
    for (int q = 0; q < 4; ++q) gload_lds16(wb[q] + k0, buf + ldsb[q]);
  };

  auto compute = [&](const f16* bA, const f16* bB) {
    __builtin_amdgcn_s_setprio(1);             // T5: favor MFMA-issuing wave
#pragma unroll
    for (int kk = 0; kk < 2; ++kk) {
      const int sl = kk * 4 + hi;
      half8 av[2], bv[4];
#pragma unroll
      for (int i = 0; i < 2; ++i)
        av[i] = *reinterpret_cast<const half8*>(
            bA + (wm * 32 + i * 16 + l15) * 64 + 8 * (sl ^ l7));
#pragma unroll
      for (int j = 0; j < 4; ++j)
        bv[j] = *reinterpret_cast<const half8*>(
            bB + (wn * 64 + j * 16 + l15) * 64 + 8 * (sl ^ l7));
#pragma unroll
      for (int i = 0; i < 2; ++i)
#pragma unroll
        for (int j = 0; j < 4; ++j)
          acc[i][j] = __builtin_amdgcn_mfma_f32_16x16x32_f16(av[i], bv[j], acc[i][j], 0, 0, 0);
    }
    __builtin_amdgcn_s_setprio(0);
  };

  auto writeA = [&](f16* buf, U4 e) {
    *reinterpret_cast<U4*>(buf + aoff) = e;
  };

  // ---- prologue: tile 0 in A0/B0; xn = x(1) in flight ----
  {
    float xa = (float)asrc[0];
    stageB(B0, 0);
    writeA(A0, expand_pack(xa));
  }
  float xn = (float)asrc[8];
  __syncthreads();

  // ---- steady state: 2 tiles per iteration, static buffers ----
  const TIN* ap = asrc + 16;                   // x(s+2) position
  const int npairs = (nsteps - 2) >> 1;
  int k = 64;                                  // staging k0 for tile s+1
  for (int p = 0; p < npairs; ++p) {
    // half A: compute tile s (A0/B0); stage B(s+1)->B1; expand x(s+1)->A1
    stageB(B1, k);
    float xa2 = (float)ap[0];                  // x(s+2), issued early
    compute(A0, B0);
    writeA(A1, expand_pack(xn));
    __syncthreads();
    // half B: compute tile s+1 (A1/B1); stage B(s+2)->B0; expand x(s+2)->A0
    stageB(B0, k + 64);
    xn = (float)ap[8];                         // x(s+3), issued early
    compute(A1, B1);
    writeA(A0, expand_pack(xa2));
    __syncthreads();
    ap += 16;
    k  += 128;
  }

  // ---- tail: tiles nsteps-2 (A0/B0) and nsteps-1 (A1/B1) ----
  stageB(B1, k);                               // k == (nsteps-1)*64
  compute(A0, B0);
  writeA(A1, expand_pack(xn));
  __syncthreads();
  compute(A1, B1);

  // ---- epilogue: Out = ns*acc (+ nb) ----
#pragma unroll
  for (int j = 0; j < 4; ++j) {
    int col   = n0 + wn * 64 + j * 16 + l15;
    float nsv = nscale[col];
    float nbv = BIAS ? nbias[col] : 0.0f;
#pragma unroll
    for (int i = 0; i < 2; ++i) {
      int rb = m0 + wm * 32 + i * 16 + hi * 4;
#pragma unroll
      for (int r = 0; r < 4; ++r)
        outz[(size_t)(rb + r) * N + col] = (TOUT)(nsv * acc[i][j][r] + nbv);
    }
  }
}

// ---------------------------------------------------------------------------
// f16 partial0 + f16 partial1 + node_bias2 + residual -> LN(256) -> exact GELU
// ---------------------------------------------------------------------------
__global__ __launch_bounds__(256)
void ln_gelu_kernel(const f16* __restrict__ P0, const f16* __restrict__ P1,
                    const float* __restrict__ X,  const float* __restrict__ nb2,
                    const float* __restrict__ gamma, const float* __restrict__ beta,
                    float* __restrict__ out, int rows) {
  int row  = blockIdx.x * 4 + (threadIdx.x >> 6);
  int lane = threadIdx.x & 63;
  if (row >= rows) return;
  const half4  a4 = *reinterpret_cast<const half4*>(P0 + (size_t)row * 256 + lane * 4);
  const half4  b4 = *reinterpret_cast<const half4*>(P1 + (size_t)row * 256 + lane * 4);
  const float4 xr = *reinterpret_cast<const float4*>(X  + (size_t)row * 256 + lane * 4);
  const float4 nb = *reinterpret_cast<const float4*>(nb2 + lane * 4);
  const float4 g  = *reinterpret_cast<const float4*>(gamma + lane * 4);
  const float4 be = *reinterpret_cast<const float4*>(beta + lane * 4);
  float h[4];
#pragma unroll
  for (int j = 0; j < 4; ++j)
    h[j] = (float)a4[j] + (float)b4[j] + (&nb.x)[j] + (&xr.x)[j];
  float s = h[0] + h[1] + h[2] + h[3];
#pragma unroll
  for (int o = 32; o >= 1; o >>= 1) s += __shfl_xor(s, o);
  float mu = s * (1.0f / 256.0f);
  float vs = 0.f;
#pragma unroll
  for (int j = 0; j < 4; ++j) { float d = h[j] - mu; vs += d * d; }
#pragma unroll
  for (int o = 32; o >= 1; o >>= 1) vs += __shfl_xor(vs, o);
  float inv = rsqrtf(vs * (1.0f / 256.0f) + 1e-5f);
  float o4[4];
#pragma unroll
  for (int j = 0; j < 4; ++j) {
    float v = (h[j] - mu) * inv * (&g.x)[j] + (&be.x)[j];
    o4[j] = 0.5f * v * (1.0f + erff(v * 0.70710678118654752f));
  }
  *reinterpret_cast<float4*>(out + (size_t)row * 256 + lane * 4) =
      make_float4(o4[0], o4[1], o4[2], o4[3]);
}

// ---------------------------------------------------------------------------
extern "C" void kernel_launch(void* const* d_in, const int* in_sizes, int n_in,
                              void* d_out, int out_size, void* d_ws, size_t ws_size,
                              hipStream_t stream) {
  (void)in_sizes; (void)n_in; (void)out_size; (void)ws_size;
  const float* x     = (const float*)d_in[0];
  const float* coef1 = (const float*)d_in[2];
  const float* sb1   = (const float*)d_in[3];
  const float* ssp1  = (const float*)d_in[4];
  const float* ns1   = (const float*)d_in[5];
  const float* nb1   = (const float*)d_in[6];
  const float* coef2 = (const float*)d_in[8];
  const float* sb2   = (const float*)d_in[9];
  const float* ssp2  = (const float*)d_in[10];
  const float* ns2   = (const float*)d_in[11];
  const float* nb2   = (const float*)d_in[12];
  const float* lgam  = (const float*)d_in[13];
  const float* lbet  = (const float*)d_in[14];
  float* out = (float*)d_out;

  const int Ntok = 16 * 1024;
  const int D0 = 256, D1 = 512, D2 = 256;

  // ws: h1 [Ntok,512] f16 (16.8MB) | part [2][Ntok,256] f16 (16.8MB) | Wt1 | Wt2
  char* ws    = (char*)d_ws;
  f16*  h1    = (f16*)ws;
  size_t off  = (size_t)Ntok * D1 * sizeof(f16);
  f16*  part  = (f16*)(ws + off);
  off += (size_t)2 * Ntok * D2 * sizeof(f16);
  f16* Wt1 = (f16*)(ws + off);
  off += (size_t)D1 * D0 * 8 * sizeof(f16);
  f16* Wt2 = (f16*)(ws + off);

  prep_w_kernel<<<(D0 * D1 + 255) / 256, 256, 0, stream>>>(coef1, ssp1, sb1, Wt1, D0, D1);
  prep_w_kernel<<<(D1 * D2 + 255) / 256, 256, 0, stream>>>(coef2, ssp2, sb2, Wt2, D1, D2);

  // layer 1: [16384 x 2048] x [512 x 2048]^T -> h1 (f16). 512 blocks, 2/CU.
  kan_gemm<true, float, f16><<<dim3(D1 / 256, Ntok / 64, 1), 512, 0, stream>>>(
      x, D0, Wt1, D0 * 8, ns1, nb1, D1, h1, D0 / 8);

  // layer 2: full-width N=256, split-K=2 -> 512 blocks; f16 partials ns2*acc.
  kan_gemm<false, f16, f16><<<dim3(D2 / 256, Ntok / 64, 2), 512, 0, stream>>>(
      h1, D1, Wt2, D1 * 8, ns2, nullptr, D2, part, D1 / 16);

  // reduce partials + bias + residual + LN + GELU
  ln_gelu_kernel<<<Ntok / 4, 256, 0, stream>>>(
      part, part + (size_t)Ntok * D2, x, nb2, lgam, lbet, out, Ntok);
}